// Round 1
// baseline (1271.375 us; speedup 1.0000x reference)
//
#include <hip/hip_runtime.h>
#include <hip/hip_bf16.h>

// LengthRegulator: conv1d(H,H,3)+LN(ch)+ReLU -> conv1d+LN+ReLU -> Linear(H,1)+ReLU
// -> durations=floor(exp(z)) -> ragged repeat_interleave of x to MAX_LEN.
// B=32, H=384, T=1024, K=3, MAX_LEN=4096. All fp32.
//
// d_out (float*): [0, B*T) durations as float, [B*T, B*T + B*H*MAX) aligned.

#define BB 32
#define HH 384
#define TTOT 1024
#define MAXL 4096
#define TT 64     // t-tile per block
#define CH 8      // input-channel chunk per LDS stage

// ---------------------------------------------------------------------------
// Transpose W [H_out, H_in, K] -> Wt [H_in*K, H_out]  (row = hi*3+k, col = h)
// so conv staging becomes a contiguous LDS memcpy.
__global__ void transpose_w_kernel(const float* __restrict__ W1,
                                   const float* __restrict__ W2,
                                   float* __restrict__ Wt1,
                                   float* __restrict__ Wt2) {
    const int row = blockIdx.x;              // 0..1151
    const float* W  = blockIdx.y ? W2 : W1;
    float* Wt       = blockIdx.y ? Wt2 : Wt1;
    const int h = threadIdx.x;               // 0..383
    Wt[row * HH + h] = W[h * (HH * 3) + row];
}

// ---------------------------------------------------------------------------
// Fused conv1d(SAME,K=3) + bias + LayerNorm(channel) + ReLU.
// PROJ=false: writes h [B,H,T].  PROJ=true: additionally dot with Wl + bl,
// ReLU, writes z [B,T] only (h2 never materialized).
// Block: 256 threads = 4 waves. Wave tt handles t-range [tt*16, tt*16+16).
// Lane ht owns channels {ht + 64*i, i=0..5}. Register tile 6h x 16t.
template <bool PROJ>
__launch_bounds__(256, 2)
__global__ void conv_ln_kernel(const float* __restrict__ X,    // [B,H,T]
                               const float* __restrict__ Wt,   // [H*3][H]
                               const float* __restrict__ bias, // [H]
                               const float* __restrict__ gain, // [H]
                               const float* __restrict__ beta, // [H]
                               const float* __restrict__ Wl,   // [H] (PROJ)
                               const float* __restrict__ blp,  // [1] (PROJ)
                               float* __restrict__ Out) {      // h [B,H,T] or z [B,T]
    __shared__ float Ws[CH * 3][HH];     // 36 KB
    __shared__ float Xs[CH][TT + 2];     // 2.1 KB

    const int b   = blockIdx.y;
    const int t0  = blockIdx.x * TT;
    const int tid = threadIdx.x;
    const int ht  = tid & 63;
    const int tt  = tid >> 6;

    float acc[6][16];
#pragma unroll
    for (int i = 0; i < 6; ++i)
#pragma unroll
        for (int u = 0; u < 16; ++u) acc[i][u] = 0.f;

    const float* Xb = X + (size_t)b * HH * TTOT;

    for (int hc = 0; hc < HH; hc += CH) {
        __syncthreads();
        // Stage W chunk: contiguous 24*384 floats starting at row hc*3.
        {
            const float4* src = (const float4*)(Wt + (size_t)hc * 3 * HH);
            float4* dst = (float4*)&Ws[0][0];
#pragma unroll
            for (int e = tid; e < (CH * 3 * HH) / 4; e += 256) dst[e] = src[e];
        }
        // Stage X chunk with SAME-padding halo: Xs[ci][j] = x[hc+ci][t0-1+j].
        for (int e = tid; e < CH * (TT + 2); e += 256) {
            const int ci = e / (TT + 2);
            const int j  = e % (TT + 2);
            const int gt = t0 - 1 + j;
            float v = 0.f;
            if (gt >= 0 && gt < TTOT) v = Xb[(size_t)(hc + ci) * TTOT + gt];
            Xs[ci][j] = v;
        }
        __syncthreads();

#pragma unroll
        for (int ci = 0; ci < CH; ++ci) {
            float xw[TT / 4 / 16 * 16 + 18];  // 18 window values
#pragma unroll
            for (int u = 0; u < 18; ++u) xw[u] = Xs[ci][tt * 16 + u];
#pragma unroll
            for (int k = 0; k < 3; ++k) {
                const float* wr = &Ws[ci * 3 + k][0];
                const float w0 = wr[ht];       const float w1 = wr[ht + 64];
                const float w2 = wr[ht + 128]; const float w3 = wr[ht + 192];
                const float w4 = wr[ht + 256]; const float w5 = wr[ht + 320];
#pragma unroll
                for (int u = 0; u < 16; ++u) {
                    const float xv = xw[u + k];
                    acc[0][u] += w0 * xv; acc[1][u] += w1 * xv;
                    acc[2][u] += w2 * xv; acc[3][u] += w3 * xv;
                    acc[4][u] += w4 * xv; acc[5][u] += w5 * xv;
                }
            }
        }
    }

    // Epilogue: bias + LayerNorm over channel dim (384) + ReLU (+ projection).
    float bia[6], gn[6], bt[6], wl[6];
#pragma unroll
    for (int i = 0; i < 6; ++i) {
        const int h = ht + 64 * i;
        bia[i] = bias[h]; gn[i] = gain[h]; bt[i] = beta[h];
        wl[i] = PROJ ? Wl[h] : 0.f;
    }

    float zloc[16];
#pragma unroll
    for (int u = 0; u < 16; ++u) {
        float s = 0.f, ss = 0.f;
#pragma unroll
        for (int i = 0; i < 6; ++i) {
            const float y = acc[i][u] + bia[i];
            acc[i][u] = y;
            s += y; ss += y * y;
        }
#pragma unroll
        for (int m = 32; m >= 1; m >>= 1) {
            s  += __shfl_xor(s, m, 64);
            ss += __shfl_xor(ss, m, 64);
        }
        const float mean = s * (1.f / HH);
        const float var  = ss * (1.f / HH) - mean * mean;
        const float inv  = rsqrtf(var + 1e-5f);
        float zsum = 0.f;
#pragma unroll
        for (int i = 0; i < 6; ++i) {
            float hv = (acc[i][u] - mean) * inv * gn[i] + bt[i];
            hv = fmaxf(hv, 0.f);
            acc[i][u] = hv;
            if (PROJ) zsum += hv * wl[i];
        }
        if (PROJ) {
#pragma unroll
            for (int m = 32; m >= 1; m >>= 1) zsum += __shfl_xor(zsum, m, 64);
            zloc[u] = zsum;
        }
    }

    if (PROJ) {
        if (ht == 0) {
            const float bl = blp[0];
#pragma unroll
            for (int u = 0; u < 16; ++u) {
                const float z = fmaxf(zloc[u] + bl, 0.f);
                Out[(size_t)b * TTOT + t0 + tt * 16 + u] = z;
            }
        }
    } else {
        float* Ob = Out + (size_t)b * HH * TTOT;
#pragma unroll
        for (int i = 0; i < 6; ++i) {
            const int h = ht + 64 * i;
            float4* p = (float4*)&Ob[(size_t)h * TTOT + t0 + tt * 16];
#pragma unroll
            for (int q = 0; q < 4; ++q)
                p[q] = make_float4(acc[i][4 * q + 0], acc[i][4 * q + 1],
                                   acc[i][4 * q + 2], acc[i][4 * q + 3]);
        }
    }
}

// ---------------------------------------------------------------------------
// durations = floor(exp(z)) (z already ReLU'd), inclusive cumsum per batch.
// One block per batch, 1024 threads.
__global__ void dur_scan_kernel(const float* __restrict__ z,
                                float* __restrict__ durOut,  // d_out[0:B*T] as float
                                int* __restrict__ cum) {
    __shared__ int sb[TTOT];
    const int b = blockIdx.x;
    const int t = threadIdx.x;
    const float zv = z[b * TTOT + t];
    const int d = (int)floorf(expf(zv));
    durOut[b * TTOT + t] = (float)d;
    sb[t] = d;
    __syncthreads();
    for (int off = 1; off < TTOT; off <<= 1) {
        const int v = (t >= off) ? sb[t - off] : 0;
        __syncthreads();
        sb[t] += v;
        __syncthreads();
    }
    cum[b * TTOT + t] = sb[t];
}

// ---------------------------------------------------------------------------
// searchsorted(cum, pos, side='right') + masked gather of x rows.
__global__ void gather_kernel(const float* __restrict__ X,   // [B,H,T]
                              const int* __restrict__ cum,   // [B,T]
                              float* __restrict__ aligned) { // [B,H,MAXL]
    __shared__ int cs[TTOT];
    const int b   = blockIdx.y;
    const int tid = threadIdx.x;
    for (int e = tid; e < TTOT; e += 256) cs[e] = cum[b * TTOT + e];
    __syncthreads();

    const int pos   = blockIdx.x * 256 + tid;
    const int total = cs[TTOT - 1];
    int lo = 0, hi = TTOT;
    while (lo < hi) {
        const int mid = (lo + hi) >> 1;
        if (cs[mid] <= pos) lo = mid + 1; else hi = mid;
    }
    const float vmul = (pos < total) ? 1.f : 0.f;
    const int idx = min(lo, TTOT - 1);

    const float* Xb = X + (size_t)b * HH * TTOT;
    float* Ab = aligned + (size_t)b * HH * MAXL;
#pragma unroll 4
    for (int h = 0; h < HH; ++h) {
        Ab[(size_t)h * MAXL + pos] = Xb[(size_t)h * TTOT + idx] * vmul;
    }
}

// ---------------------------------------------------------------------------
extern "C" void kernel_launch(void* const* d_in, const int* in_sizes, int n_in,
                              void* d_out, int out_size, void* d_ws, size_t ws_size,
                              hipStream_t stream) {
    const float* x   = (const float*)d_in[0];   // [B,H,T]
    const float* W1  = (const float*)d_in[1];   // [H,H,3]
    const float* b1  = (const float*)d_in[2];
    const float* g1  = (const float*)d_in[3];
    const float* be1 = (const float*)d_in[4];
    const float* W2  = (const float*)d_in[5];
    const float* b2  = (const float*)d_in[6];
    const float* g2  = (const float*)d_in[7];
    const float* be2 = (const float*)d_in[8];
    const float* Wl  = (const float*)d_in[9];   // [H,1]
    const float* bl  = (const float*)d_in[10];  // [1]

    float* out = (float*)d_out;
    float* durOut = out;                         // [B,T] as float
    float* aligned = out + (size_t)BB * TTOT;    // [B,H,MAXL]

    // Workspace layout (bytes):
    char* ws = (char*)d_ws;
    const size_t wtBytes  = (size_t)HH * 3 * HH * sizeof(float);    // 1.77 MB
    const size_t h1Bytes  = (size_t)BB * HH * TTOT * sizeof(float); // 50.3 MB
    const size_t ztBytes  = (size_t)BB * TTOT * sizeof(float);      // 128 KB
    float* Wt1 = (float*)(ws);
    float* Wt2 = (float*)(ws + wtBytes);
    float* h1  = (float*)(ws + 2 * wtBytes);
    float* zb  = (float*)(ws + 2 * wtBytes + h1Bytes);
    int*   cum = (int*)  (ws + 2 * wtBytes + h1Bytes + ztBytes);

    // 1) transpose weights
    transpose_w_kernel<<<dim3(HH * 3, 2), HH, 0, stream>>>(W1, W2, Wt1, Wt2);
    // 2) conv1 + LN + ReLU -> h1
    conv_ln_kernel<false><<<dim3(TTOT / TT, BB), 256, 0, stream>>>(
        x, Wt1, b1, g1, be1, nullptr, nullptr, h1);
    // 3) conv2 + LN + ReLU + proj -> z
    conv_ln_kernel<true><<<dim3(TTOT / TT, BB), 256, 0, stream>>>(
        h1, Wt2, b2, g2, be2, Wl, bl, zb);
    // 4) durations + per-batch inclusive scan
    dur_scan_kernel<<<BB, TTOT, 0, stream>>>(zb, durOut, cum);
    // 5) searchsorted + gather
    gather_kernel<<<dim3(MAXL / 256, BB), 256, 0, stream>>>(x, cum, aligned);
}

// Round 3
// 515.759 us; speedup vs baseline: 2.4651x; 2.4651x over previous
//
#include <hip/hip_runtime.h>
#include <hip/hip_bf16.h>

// LengthRegulator on MI355X — R3 (= R2 resubmit after infra failure):
// convs as f16-split-2 MFMA GEMMs (3 products, scaled cross terms), fp32
// everywhere else. Layout:
//   d_out: [0,B*T) durations (as float), [B*T, ...) aligned [B,H,MAXL].
//   h_raw (fp32 [b][t][384]) aliases the aligned region (gather runs last).

#define BB 32
#define HHD 384
#define TTOT 1024
#define MAXL 4096

typedef _Float16 half8 __attribute__((ext_vector_type(8)));
typedef float floatx4 __attribute__((ext_vector_type(4)));

// ---------------------------------------------------------------------------
// prep_w: W[h][hi][k] fp32 -> Wq[s] f16, layout e = ((c*3+k)*384 + h)*32 + d,
// where c = hi/32, d = hi%32. Split: hi = f16(w), lo = f16((w-hi)*2048).
__global__ void prep_w_kernel(const float* __restrict__ W1,
                              const float* __restrict__ W2,
                              _Float16* __restrict__ q1h, _Float16* __restrict__ q1l,
                              _Float16* __restrict__ q2h, _Float16* __restrict__ q2l) {
    const int e = blockIdx.x * 256 + threadIdx.x;     // < 442368
    const float* W = blockIdx.y ? W2 : W1;
    _Float16* oh = blockIdx.y ? q2h : q1h;
    _Float16* ol = blockIdx.y ? q2l : q1l;
    const int d  = e & 31;
    const int m  = (e >> 5) % 384;
    const int ck = e / (32 * 384);
    const int c  = ck / 3, k = ck - 3 * c;
    const float w = W[(size_t)m * 1152 + (size_t)(32 * c + d) * 3 + k];
    const _Float16 hi = (_Float16)w;
    oh[e] = hi;
    ol[e] = (_Float16)((w - (float)hi) * 2048.0f);
}

// ---------------------------------------------------------------------------
// prep_x: x[b][h][t] fp32 -> Xt1/Xt2 f16 [b][t][384] (transposed + split).
__global__ void prep_x_kernel(const float* __restrict__ X,
                              _Float16* __restrict__ o1,
                              _Float16* __restrict__ o2) {
    __shared__ float Ls[64][65];
    const int h0 = blockIdx.x * 64;
    const int t0 = blockIdx.y * 64;
    const int b  = blockIdx.z;
    const int tid = threadIdx.x;
    const int tl = tid & 63, hq = tid >> 6;
    const float* Xb = X + (size_t)b * HHD * TTOT;
#pragma unroll
    for (int i = 0; i < 16; ++i) {
        const int h = i * 4 + hq;
        Ls[tl][h] = Xb[(size_t)(h0 + h) * TTOT + t0 + tl];
    }
    __syncthreads();
#pragma unroll
    for (int i = 0; i < 16; ++i) {
        const int t = i * 4 + hq;
        const float v = Ls[t][tl];
        const _Float16 a = (_Float16)v;
        const size_t o = ((size_t)b * TTOT + t0 + t) * HHD + h0 + tl;
        o1[o] = a;
        o2[o] = (_Float16)((v - (float)a) * 2048.0f);
    }
}

// ---------------------------------------------------------------------------
// conv_mfma: C[96 m][128 t] per block. K = 12 chunks x (3 k-steps of 32).
// A = Wq (pre-split f16), B = Xt/H1t [b][t][384] splits (halo via t-shift).
// acc_hh += a1*b1 ; acc_x += a1*b2' + a2'*b1 ; out = acc_hh + acc_x/2048 + bias.
// 4 waves, wave tile 48x64. LDS 66,880 B -> 2 blocks/CU.
__launch_bounds__(256, 2)
__global__ void conv_mfma_kernel(const _Float16* __restrict__ Bh,  // [b][t][384]
                                 const _Float16* __restrict__ Bl,
                                 const _Float16* __restrict__ Ah,  // Wq hi
                                 const _Float16* __restrict__ Al,  // Wq lo
                                 const float* __restrict__ bias,
                                 float* __restrict__ Out) {        // h_raw [b][t][384]
    __shared__ __align__(16) _Float16 sm[33440];  // W: [2][3][96][40] @0, X: [2][130][40] @23040
    const int tid  = threadIdx.x;
    const int lane = tid & 63, wid = tid >> 6;
    const int wm = wid >> 1, wn = wid & 1;
    const int l15 = lane & 15, g4 = lane >> 4;
    const int h0 = blockIdx.x * 96;
    const int t0 = blockIdx.y * 128;
    const int b  = blockIdx.z;

    floatx4 ahh[3][4], axx[3][4];
#pragma unroll
    for (int mt = 0; mt < 3; ++mt)
#pragma unroll
        for (int nt = 0; nt < 4; ++nt) {
            ahh[mt][nt] = (floatx4){0.f, 0.f, 0.f, 0.f};
            axx[mt][nt] = (floatx4){0.f, 0.f, 0.f, 0.f};
        }

    const size_t xbase = (size_t)b * TTOT * HHD;

    for (int ch = 0; ch < 12; ++ch) {
        __syncthreads();
        // --- stage W chunk: 2 splits x 3 k x 96 rows x 32 f16 (2304 quads) ---
#pragma unroll
        for (int it = 0; it < 9; ++it) {
            const int e  = tid + it * 256;
            const int s  = e / 1152;
            const int r1 = e - s * 1152;
            const int k  = r1 / 384;
            const int q  = r1 - k * 384;
            const int m  = q >> 2, c8 = (q & 3) << 3;
            const _Float16* src = (s ? Al : Ah) +
                ((size_t)((ch * 3 + k) * 384 + h0 + m) << 5) + c8;
            const uint4 v = *(const uint4*)src;
            *(uint4*)&sm[((s * 3 + k) * 96 + m) * 40 + c8] = v;
        }
        // --- stage X chunk: 2 splits x 130 rows (halo) x 32 f16 (1040 quads) ---
#pragma unroll
        for (int it = 0; it < 5; ++it) {
            const int e = tid + it * 256;
            if (e < 1040) {
                const int s  = e / 520;
                const int r1 = e - s * 520;
                const int j  = r1 >> 2, q = r1 & 3;
                const int gt = t0 - 1 + j;
                uint4 v = make_uint4(0u, 0u, 0u, 0u);
                if (gt >= 0 && gt < TTOT) {
                    const _Float16* src = (s ? Bl : Bh) + xbase +
                        (size_t)gt * HHD + ch * 32 + (q << 3);
                    v = *(const uint4*)src;
                }
                *(uint4*)&sm[23040 + (s * 130 + j) * 40 + (q << 3)] = v;
            }
        }
        __syncthreads();

#pragma unroll
        for (int k = 0; k < 3; ++k) {
            half8 ah[3], al[3], bh[4], bl[4];
#pragma unroll
            for (int mt = 0; mt < 3; ++mt) {
                const int m = wm * 48 + mt * 16 + l15;
                ah[mt] = *(const half8*)&sm[((0 + k) * 96 + m) * 40 + g4 * 8];
                al[mt] = *(const half8*)&sm[((3 + k) * 96 + m) * 40 + g4 * 8];
            }
#pragma unroll
            for (int nt = 0; nt < 4; ++nt) {
                const int j = wn * 64 + nt * 16 + l15 + k;
                bh[nt] = *(const half8*)&sm[23040 + (0   + j) * 40 + g4 * 8];
                bl[nt] = *(const half8*)&sm[23040 + (130 + j) * 40 + g4 * 8];
            }
#pragma unroll
            for (int mt = 0; mt < 3; ++mt)
#pragma unroll
                for (int nt = 0; nt < 4; ++nt) {
                    ahh[mt][nt] = __builtin_amdgcn_mfma_f32_16x16x32_f16(
                        ah[mt], bh[nt], ahh[mt][nt], 0, 0, 0);
                    axx[mt][nt] = __builtin_amdgcn_mfma_f32_16x16x32_f16(
                        ah[mt], bl[nt], axx[mt][nt], 0, 0, 0);
                    axx[mt][nt] = __builtin_amdgcn_mfma_f32_16x16x32_f16(
                        al[mt], bh[nt], axx[mt][nt], 0, 0, 0);
                }
        }
    }

    // --- epilogue: recombine, transpose via LDS, coalesced [b][t][h] write ---
    __syncthreads();
    float* Lt = (float*)sm;  // [128][100]
#pragma unroll
    for (int mt = 0; mt < 3; ++mt)
#pragma unroll
        for (int nt = 0; nt < 4; ++nt) {
            const int row = wn * 64 + nt * 16 + l15;     // t within tile
            const int col = wm * 48 + mt * 16 + g4 * 4;  // h within tile
            float4 v;
            v.x = ahh[mt][nt][0] + axx[mt][nt][0] * (1.0f / 2048.0f);
            v.y = ahh[mt][nt][1] + axx[mt][nt][1] * (1.0f / 2048.0f);
            v.z = ahh[mt][nt][2] + axx[mt][nt][2] * (1.0f / 2048.0f);
            v.w = ahh[mt][nt][3] + axx[mt][nt][3] * (1.0f / 2048.0f);
            *(float4*)&Lt[row * 100 + col] = v;
        }
    __syncthreads();
    const size_t obase = ((size_t)b * TTOT + t0) * HHD + h0;
#pragma unroll
    for (int i = 0; i < 12; ++i) {
        const int e = tid + i * 256;
        const int row = e / 24, c4 = (e - row * 24) * 4;
        float4 v = *(const float4*)&Lt[row * 100 + c4];
        const float4 bv = *(const float4*)&bias[h0 + c4];
        v.x += bv.x; v.y += bv.y; v.z += bv.z; v.w += bv.w;
        *(float4*)&Out[obase + (size_t)row * HHD + c4] = v;
    }
}

// ---------------------------------------------------------------------------
// ln_split: LayerNorm(ch) + ReLU on h_raw [row=b*T+t][384], emit f16 splits.
__global__ void ln_split_kernel(const float* __restrict__ hraw,
                                const float* __restrict__ g,
                                const float* __restrict__ be,
                                _Float16* __restrict__ o1,
                                _Float16* __restrict__ o2) {
    const int row = blockIdx.x * 4 + (threadIdx.x >> 6);
    const int ln  = threadIdx.x & 63;
    const float* src = hraw + (size_t)row * HHD;
    float v[6], s = 0.f, ss = 0.f;
#pragma unroll
    for (int j = 0; j < 6; ++j) { v[j] = src[ln + 64 * j]; s += v[j]; ss += v[j] * v[j]; }
#pragma unroll
    for (int m = 32; m >= 1; m >>= 1) { s += __shfl_xor(s, m, 64); ss += __shfl_xor(ss, m, 64); }
    const float mean = s * (1.f / HHD);
    const float var  = ss * (1.f / HHD) - mean * mean;
    const float inv  = rsqrtf(var + 1e-5f);
#pragma unroll
    for (int j = 0; j < 6; ++j) {
        const int h = ln + 64 * j;
        float y = (v[j] - mean) * inv * g[h] + be[h];
        y = fmaxf(y, 0.f);
        const _Float16 a = (_Float16)y;
        const size_t o = (size_t)row * HHD + h;
        o1[o] = a;
        o2[o] = (_Float16)((y - (float)a) * 2048.0f);
    }
}

// ---------------------------------------------------------------------------
// ln_proj: LayerNorm + ReLU + dot(Wl) + bl + ReLU -> z[row].
__global__ void ln_proj_kernel(const float* __restrict__ hraw,
                               const float* __restrict__ g,
                               const float* __restrict__ be,
                               const float* __restrict__ Wl,
                               const float* __restrict__ blp,
                               float* __restrict__ zb) {
    const int row = blockIdx.x * 4 + (threadIdx.x >> 6);
    const int ln  = threadIdx.x & 63;
    const float* src = hraw + (size_t)row * HHD;
    float v[6], s = 0.f, ss = 0.f;
#pragma unroll
    for (int j = 0; j < 6; ++j) { v[j] = src[ln + 64 * j]; s += v[j]; ss += v[j] * v[j]; }
#pragma unroll
    for (int m = 32; m >= 1; m >>= 1) { s += __shfl_xor(s, m, 64); ss += __shfl_xor(ss, m, 64); }
    const float mean = s * (1.f / HHD);
    const float inv  = rsqrtf(ss * (1.f / HHD) - mean * mean + 1e-5f);
    float zs = 0.f;
#pragma unroll
    for (int j = 0; j < 6; ++j) {
        const int h = ln + 64 * j;
        float y = (v[j] - mean) * inv * g[h] + be[h];
        zs += fmaxf(y, 0.f) * Wl[h];
    }
#pragma unroll
    for (int m = 32; m >= 1; m >>= 1) zs += __shfl_xor(zs, m, 64);
    if (ln == 0) zb[row] = fmaxf(zs + blp[0], 0.f);
}

// ---------------------------------------------------------------------------
__global__ void dur_scan_kernel(const float* __restrict__ z,
                                float* __restrict__ durOut,
                                int* __restrict__ cum) {
    __shared__ int sb[TTOT];
    const int b = blockIdx.x;
    const int t = threadIdx.x;
    const int d = (int)floorf(expf(z[b * TTOT + t]));
    durOut[b * TTOT + t] = (float)d;
    sb[t] = d;
    __syncthreads();
    for (int off = 1; off < TTOT; off <<= 1) {
        const int v = (t >= off) ? sb[t - off] : 0;
        __syncthreads();
        sb[t] += v;
        __syncthreads();
    }
    cum[b * TTOT + t] = sb[t];
}

// ---------------------------------------------------------------------------
__global__ void gather_kernel(const float* __restrict__ X,
                              const int* __restrict__ cum,
                              float* __restrict__ aligned) {
    __shared__ int cs[TTOT];
    const int b   = blockIdx.y;
    const int tid = threadIdx.x;
    for (int e = tid; e < TTOT; e += 256) cs[e] = cum[b * TTOT + e];
    __syncthreads();
    const int pos   = blockIdx.x * 256 + tid;
    const int total = cs[TTOT - 1];
    int lo = 0, hi = TTOT;
    while (lo < hi) {
        const int mid = (lo + hi) >> 1;
        if (cs[mid] <= pos) lo = mid + 1; else hi = mid;
    }
    const float vmul = (pos < total) ? 1.f : 0.f;
    const int idx = min(lo, TTOT - 1);
    const float* Xb = X + (size_t)b * HHD * TTOT;
    float* Ab = aligned + (size_t)b * HHD * MAXL;
#pragma unroll 4
    for (int h = 0; h < HHD; ++h)
        Ab[(size_t)h * MAXL + pos] = Xb[(size_t)h * TTOT + idx] * vmul;
}

// ---------------------------------------------------------------------------
extern "C" void kernel_launch(void* const* d_in, const int* in_sizes, int n_in,
                              void* d_out, int out_size, void* d_ws, size_t ws_size,
                              hipStream_t stream) {
    const float* x   = (const float*)d_in[0];
    const float* W1  = (const float*)d_in[1];
    const float* b1  = (const float*)d_in[2];
    const float* g1  = (const float*)d_in[3];
    const float* be1 = (const float*)d_in[4];
    const float* W2  = (const float*)d_in[5];
    const float* b2  = (const float*)d_in[6];
    const float* g2  = (const float*)d_in[7];
    const float* be2 = (const float*)d_in[8];
    const float* Wl  = (const float*)d_in[9];
    const float* bl  = (const float*)d_in[10];

    float* out     = (float*)d_out;
    float* durOut  = out;                        // [B*T]
    float* aligned = out + (size_t)BB * TTOT;    // [B*H*MAXL]
    float* h_raw   = aligned;                    // 50.3 MB alias; gather runs last

    char* ws = (char*)d_ws;
    const size_t wqB = (size_t)442368 * sizeof(_Float16);          // 884,736 B each
    const size_t xtB = (size_t)BB * TTOT * HHD * sizeof(_Float16); // 25.2 MB each
    _Float16* Wq1h = (_Float16*)(ws);
    _Float16* Wq1l = (_Float16*)(ws + wqB);
    _Float16* Wq2h = (_Float16*)(ws + 2 * wqB);
    _Float16* Wq2l = (_Float16*)(ws + 3 * wqB);
    _Float16* Xt1  = (_Float16*)(ws + 4 * wqB);          // reused as H1t1
    _Float16* Xt2  = (_Float16*)(ws + 4 * wqB + xtB);    // reused as H1t2
    float*    zb   = (float*)   (ws + 4 * wqB + 2 * xtB);
    int*      cum  = (int*)     (ws + 4 * wqB + 2 * xtB + (size_t)BB * TTOT * 4);

    prep_w_kernel<<<dim3(1728, 2), 256, 0, stream>>>(W1, W2, Wq1h, Wq1l, Wq2h, Wq2l);
    prep_x_kernel<<<dim3(6, 16, 32), 256, 0, stream>>>(x, Xt1, Xt2);
    conv_mfma_kernel<<<dim3(4, 8, 32), 256, 0, stream>>>(Xt1, Xt2, Wq1h, Wq1l, b1, h_raw);
    ln_split_kernel<<<8192, 256, 0, stream>>>(h_raw, g1, be1, Xt1, Xt2);
    conv_mfma_kernel<<<dim3(4, 8, 32), 256, 0, stream>>>(Xt1, Xt2, Wq2h, Wq2l, b2, h_raw);
    ln_proj_kernel<<<8192, 256, 0, stream>>>(h_raw, g2, be2, Wl, bl, zb);
    dur_scan_kernel<<<BB, TTOT, 0, stream>>>(zb, durOut, cum);
    gather_kernel<<<dim3(MAXL / 256, BB), 256, 0, stream>>>(x, cum, aligned);
}